// Round 5
// baseline (620.914 us; speedup 1.0000x reference)
//
#include <hip/hip_runtime.h>
#include <stdint.h>

// LinearSelfAttention: out = ((phi(xWq) @ (phi(xWk)^T V)) / Z) @ Wo
// B=4 S=8192 H=16 Dh=64 F=128 Dm=1024. All GEMMs bf16-MFMA/fp32-acc.
// R5: 256^2-tile 8-wave GEMMs with 4-slot BK=32 counted-vmcnt pipeline
//     (T3+T4: stages 3 K-tiles deep, vmcnt(12) steady state, raw s_barrier),
//     chunk-XOR LDS swizzle (T2), setprio (T5). phi fused per-wave (wave=head).

#define DEVINL __device__ __forceinline__

typedef float f32x4 __attribute__((ext_vector_type(4)));
typedef __bf16 bf16x8 __attribute__((ext_vector_type(8)));
typedef unsigned short u16;

DEVINL u16 f2bf(float f) {
  union { float f; uint32_t u; } v; v.f = f;
  uint32_t u = v.u;
  u += 0x7fffu + ((u >> 16) & 1u);   // round-to-nearest-even
  return (u16)(u >> 16);
}
DEVINL float bf2f(u16 h) {
  union { uint32_t u; float f; } v; v.u = ((uint32_t)h) << 16;
  return v.f;
}

#define GLOAD16(gp, lp) __builtin_amdgcn_global_load_lds( \
    (const __attribute__((address_space(1))) unsigned int*)(gp), \
    (__attribute__((address_space(3))) unsigned int*)(lp), 16, 0, 0)

// ---------------- 256^2 pipelined GEMM machinery ----------------
// Slot: A [256 rows][32 k] + B [256 rows][32 k], 16 KiB each, swizzled:
// LDS[row][u] holds global[row][u ^ ((row>>2)&3)] (16B chunks, 4/row).
// 4 slots = 128 KiB. Stage = 4 gload_lds/thread/K-tile (512 threads).

DEVINL void stage_tile(const u16* gA, const u16* gB, u16* sl, int kt,
                       int wave, int lane) {
  const uint8_t* a8 = (const uint8_t*)gA + (size_t)kt * 64;
  const uint8_t* b8 = (const uint8_t*)gB + (size_t)kt * 64;
#pragma unroll
  for (int j = 0; j < 2; ++j) {
    int row = j * 128 + wave * 16 + (lane >> 2);
    int gch = (lane & 3) ^ ((row >> 2) & 3);
    GLOAD16(a8 + (size_t)row * 2048 + (size_t)gch * 16,
            (uint8_t*)sl + (size_t)(j * 128 + wave * 16) * 64);
    GLOAD16(b8 + (size_t)row * 2048 + (size_t)gch * 16,
            (uint8_t*)(sl + 8192) + (size_t)(j * 128 + wave * 16) * 64);
  }
}

DEVINL bf16x8 fragrd(const u16* base, int row, int lane) {
  int ch = (lane >> 4) ^ ((row >> 2) & 3);
  return *(const bf16x8*)&base[(size_t)row * 32 + ch * 8];
}

// main loop: 32 K-tiles of 32; acc[8][4] per wave (128x64 C per wave).
DEVINL void gemm_main(const u16* gA, const u16* gB, u16* smem,
                      f32x4 acc[8][4], int wave, int lane, int wr, int wc) {
  stage_tile(gA, gB, smem + 0 * 16384, 0, wave, lane);
  stage_tile(gA, gB, smem + 1 * 16384, 1, wave, lane);
  stage_tile(gA, gB, smem + 2 * 16384, 2, wave, lane);
  for (int t = 0; t < 32; ++t) {
    u16* sl = smem + (size_t)(t & 3) * 16384;
    if (t < 29) {
      stage_tile(gA, gB, smem + (size_t)((t + 3) & 3) * 16384, t + 3, wave, lane);
      asm volatile("s_waitcnt vmcnt(12)" ::: "memory");
    } else if (t == 29) {
      asm volatile("s_waitcnt vmcnt(8)" ::: "memory");
    } else if (t == 30) {
      asm volatile("s_waitcnt vmcnt(4)" ::: "memory");
    } else {
      asm volatile("s_waitcnt vmcnt(0)" ::: "memory");
    }
    __builtin_amdgcn_s_barrier();
    bf16x8 bfr[4];
#pragma unroll
    for (int n = 0; n < 4; ++n)
      bfr[n] = fragrd(sl + 8192, wc * 64 + n * 16 + (lane & 15), lane);
    __builtin_amdgcn_s_setprio(1);
#pragma unroll
    for (int am = 0; am < 8; ++am) {
      bf16x8 af = fragrd(sl, wr * 128 + am * 16 + (lane & 15), lane);
#pragma unroll
      for (int n = 0; n < 4; ++n)
        acc[am][n] = __builtin_amdgcn_mfma_f32_16x16x32_bf16(af, bfr[n], acc[am][n], 0, 0, 0);
    }
    __builtin_amdgcn_s_setprio(0);
    __builtin_amdgcn_s_barrier();
  }
}

// ---- linear staging helpers (small kernels keep 128-tile structure) ----
template <int ROWS>
DEVINL void stage_r128(const uint8_t* g, size_t stride, u16* lds, int wave, int lane) {
#pragma unroll
  for (int j = 0; j < ROWS / 32; ++j) {
    int row = wave * (ROWS / 4) + j * 8 + (lane >> 3);
    GLOAD16(g + (size_t)row * stride + (size_t)(lane & 7) * 16,
            (uint8_t*)lds + (size_t)(wave * (ROWS / 4) + j * 8) * 128);
  }
}
template <int ROWS>
DEVINL void stage_r256(const uint8_t* g, size_t stride, u16* lds, int wave, int lane) {
#pragma unroll
  for (int j = 0; j < ROWS / 16; ++j) {
    int row = wave * (ROWS / 4) + j * 4 + (lane >> 4);
    GLOAD16(g + (size_t)row * stride + (size_t)(lane & 15) * 16,
            (uint8_t*)lds + (size_t)(wave * (ROWS / 4) + j * 4) * 256);
  }
}

// ---------------- prep kernels ----------------

__global__ __launch_bounds__(256) void cast_x_kernel(
    const float* __restrict__ src, u16* __restrict__ dst, long n4) {
  long i = (long)blockIdx.x * 256 + threadIdx.x;
  const long stride = (long)gridDim.x * 256;
  const float4* s4 = (const float4*)src;
  uint2* d4 = (uint2*)dst;
  for (; i < n4; i += stride) {
    float4 v = s4[i];
    uint2 o;
    o.x = (uint32_t)f2bf(v.x) | ((uint32_t)f2bf(v.y) << 16);
    o.y = (uint32_t)f2bf(v.z) | ((uint32_t)f2bf(v.w) << 16);
    d4[i] = o;
  }
}

// src fp32 [R][C] -> dst bf16 [C][R]
__global__ __launch_bounds__(256) void transpose_cast_kernel(
    const float* __restrict__ src, u16* __restrict__ dst, int R, int C) {
  __shared__ float tile[32 * 33];
  const int ntr = R >> 5;
  const int tr = blockIdx.x % ntr, tc = blockIdx.x / ntr;
  const int tid = threadIdx.x;
  {
    int r = tid >> 3, c4 = (tid & 7) * 4;
    float4 v = *(const float4*)&src[(size_t)(tr * 32 + r) * C + tc * 32 + c4];
    tile[r * 33 + c4 + 0] = v.x;
    tile[r * 33 + c4 + 1] = v.y;
    tile[r * 33 + c4 + 2] = v.z;
    tile[r * 33 + c4 + 3] = v.w;
  }
  __syncthreads();
  {
    int c = tid >> 3, r4 = (tid & 7) * 4;
    uint2 o;
    o.x = (uint32_t)f2bf(tile[(r4 + 0) * 33 + c]) |
          ((uint32_t)f2bf(tile[(r4 + 1) * 33 + c]) << 16);
    o.y = (uint32_t)f2bf(tile[(r4 + 2) * 33 + c]) |
          ((uint32_t)f2bf(tile[(r4 + 3) * 33 + c]) << 16);
    *(uint2*)&dst[(size_t)(tc * 32 + c) * R + tr * 32 + r4] = o;
  }
}

// ---------------- QKV GEMM (256^2 tiles) + fused phi ----------------
// N = 3072: tn 0..3 Q, 4..7 K, 8..11 V. Wave (wr,wc): C rows wr*128+[0,128),
// cols wc*64+[0,64) -> each wave owns head (tn&3)*4+wc, all d.
__global__ __launch_bounds__(512, 2) void gemm_qkv_phi_kernel(
    const u16* __restrict__ xb, const u16* __restrict__ wT,
    const u16* __restrict__ rfT,
    u16* __restrict__ Qp, u16* __restrict__ KpT, u16* __restrict__ VhT) {
  __shared__ u16 smem[65536];   // 128 KiB: 4 slots; epilogue: per-wave patches
  const int tid = threadIdx.x, lane = tid & 63, wave = tid >> 6;
  const int wr = wave >> 2, wc = wave & 3;
  const int xcd = blockIdx.x & 7, ii = blockIdx.x >> 3;   // 1536 = 8*192
  const int tn = ii % 12, tm = xcd * 16 + ii / 12;        // tm-major per XCD
  const int tensor = tn >> 2;

  f32x4 acc[8][4];
#pragma unroll
  for (int m = 0; m < 8; ++m)
#pragma unroll
    for (int n = 0; n < 4; ++n) acc[m][n] = (f32x4){0.f, 0.f, 0.f, 0.f};

  const u16* gA = xb + (size_t)tm * 256 * 1024;
  const u16* gB = wT + (size_t)tn * 256 * 1024;
  gemm_main(gA, gB, smem, acc, wave, lane, wr, wc);

  // ---- epilogue: per-wave private patch [*][72] (4608 u16) ----
  u16* patch = smem + (size_t)wave * 4608;
  const int b = tm >> 5;
  const int h = (tn & 3) * 4 + wc;
  const size_t bh = (size_t)b * 16 + h;
  const int sb = (tm & 31) * 256 + wr * 128;
  const float SC = 0.088388347648318447f;  // 128^-0.5

  if (tensor == 2) {
    // V -> VhT[b,h,d,s]; per s-half: patch [64 d][72] cols s_l
#pragma unroll
    for (int sh = 0; sh < 2; ++sh) {
#pragma unroll
      for (int q = 0; q < 4; ++q)
#pragma unroll
        for (int n = 0; n < 4; ++n) {
          int d = n * 16 + (lane & 15);
          int s_l = q * 16 + (lane >> 4) * 4;
#pragma unroll
          for (int r = 0; r < 4; ++r)
            patch[d * 72 + s_l + r] = f2bf(acc[sh * 4 + q][n][r]);
        }
#pragma unroll
      for (int it = 0; it < 8; ++it) {
        int d = it * 8 + (lane >> 3);
        *(uint4*)&VhT[(bh * 64 + d) * 8192 + sb + sh * 64 + (lane & 7) * 8] =
            *(const uint4*)&patch[d * 72 + (lane & 7) * 8];
      }
    }
    return;
  }

  // Q/K: phi per 64-row chunk
#pragma unroll
  for (int ch = 0; ch < 2; ++ch) {
    // (a) GEMM chunk -> patch [64 s][72] cols d
#pragma unroll
    for (int q = 0; q < 4; ++q)
#pragma unroll
      for (int n = 0; n < 4; ++n) {
        int d = n * 16 + (lane & 15);
        int s_l = q * 16 + (lane >> 4) * 4;
#pragma unroll
        for (int r = 0; r < 4; ++r)
          patch[(s_l + r) * 72 + d] = f2bf(acc[ch * 4 + q][n][r]);
      }
    // (b) A-frags into regs
    bf16x8 af[4][2];
#pragma unroll
    for (int fm = 0; fm < 4; ++fm)
#pragma unroll
      for (int kk = 0; kk < 2; ++kk)
        af[fm][kk] = *(const bf16x8*)&patch[(size_t)(fm * 16 + (lane & 15)) * 72 +
                                            kk * 32 + (lane >> 4) * 8];
    // (c/d) per f-half: MFMA vs rf (global, L2-hot), cos/sin, store
#pragma unroll
    for (int fh = 0; fh < 2; ++fh) {
      f32x4 pacc[4][4];
#pragma unroll
      for (int fm = 0; fm < 4; ++fm)
#pragma unroll
        for (int nn = 0; nn < 4; ++nn) pacc[fm][nn] = (f32x4){0.f, 0.f, 0.f, 0.f};
#pragma unroll
      for (int kk = 0; kk < 2; ++kk)
#pragma unroll
        for (int nn = 0; nn < 4; ++nn) {
          int f = (fh * 4 + nn) * 16 + (lane & 15);
          bf16x8 bb = *(const bf16x8*)&rfT[(size_t)f * 64 + kk * 32 + (lane >> 4) * 8];
#pragma unroll
          for (int fm = 0; fm < 4; ++fm)
            pacc[fm][nn] = __builtin_amdgcn_mfma_f32_16x16x32_bf16(af[fm][kk], bb, pacc[fm][nn], 0, 0, 0);
        }
#pragma unroll
      for (int fm = 0; fm < 4; ++fm)
#pragma unroll
        for (int nn = 0; nn < 4; ++nn) {
          int f_l = nn * 16 + (lane & 15);
          int s_l = fm * 16 + (lane >> 4) * 4;
#pragma unroll
          for (int r = 0; r < 4; ++r) {
            float pv = pacc[fm][nn][r];
            float v = (fh == 0 ? __cosf(pv) : __sinf(pv)) * SC;
            if (tensor == 0) patch[(s_l + r) * 72 + f_l] = f2bf(v);
            else             patch[f_l * 72 + s_l + r]   = f2bf(v);
          }
        }
      if (tensor == 0) {
#pragma unroll
        for (int it = 0; it < 8; ++it) {
          int s_l = it * 8 + (lane >> 3);
          *(uint4*)&Qp[(bh * 8192 + sb + ch * 64 + s_l) * 128 + fh * 64 + (lane & 7) * 8] =
              *(const uint4*)&patch[s_l * 72 + (lane & 7) * 8];
        }
      } else {
#pragma unroll
        for (int it = 0; it < 8; ++it) {
          int f_l = it * 8 + (lane >> 3);
          *(uint4*)&KpT[(bh * 128 + fh * 64 + f_l) * 8192 + sb + ch * 64 + (lane & 7) * 8] =
              *(const uint4*)&patch[f_l * 72 + (lane & 7) * 8];
        }
      }
    }
  }
}

// ---------------- KV = Kp^T V + Ksum, partial over s-chunks ----------------
__global__ __launch_bounds__(256) void kv_partial_kernel(
    const u16* __restrict__ KpT, const u16* __restrict__ VhT,
    float* __restrict__ partial) {
  __shared__ u16 smem2[12288];
  __shared__ float ksmem[256];
  u16* As = smem2;        // [128 f][64 s]
  u16* Bs = smem2 + 8192; // [64 d][64 s]
  const int tid = threadIdx.x, lane = tid & 63, wave = tid >> 6;
  const int bh = blockIdx.x >> 3, ch = blockIdx.x & 7;
  const uint8_t* aB = (const uint8_t*)(KpT + (size_t)bh * 128 * 8192 + ch * 1024);
  const uint8_t* bB = (const uint8_t*)(VhT + (size_t)bh * 64 * 8192 + ch * 1024);

  f32x4 acc[2][4];
#pragma unroll
  for (int m = 0; m < 2; ++m)
#pragma unroll
    for (int n = 0; n < 4; ++n) acc[m][n] = (f32x4){0.f, 0.f, 0.f, 0.f};
  float ks = 0.f;
  const int fK = tid >> 1, sO = (tid & 1) * 32;

  for (int t = 0; t < 16; ++t) {
    stage_r128<128>(aB + t * 128, 16384, As, wave, lane);
    stage_r128<64>(bB + t * 128, 16384, Bs, wave, lane);
    __syncthreads();
#pragma unroll
    for (int i = 0; i < 4; ++i) {
      uint4 v = *(const uint4*)&As[fK * 64 + sO + i * 8];
      ks += bf2f((u16)(v.x & 0xffff)) + bf2f((u16)(v.x >> 16));
      ks += bf2f((u16)(v.y & 0xffff)) + bf2f((u16)(v.y >> 16));
      ks += bf2f((u16)(v.z & 0xffff)) + bf2f((u16)(v.z >> 16));
      ks += bf2f((u16)(v.w & 0xffff)) + bf2f((u16)(v.w >> 16));
    }
#pragma unroll
    for (int kk = 0; kk < 2; ++kk) {
      const int ko = kk * 32 + (lane >> 4) * 8;
      bf16x8 a[2], bb[4];
#pragma unroll
      for (int m = 0; m < 2; ++m)
        a[m] = *(const bf16x8*)&As[(size_t)(wave * 32 + m * 16 + (lane & 15)) * 64 + ko];
#pragma unroll
      for (int n = 0; n < 4; ++n)
        bb[n] = *(const bf16x8*)&Bs[(size_t)(n * 16 + (lane & 15)) * 64 + ko];
#pragma unroll
      for (int m = 0; m < 2; ++m)
#pragma unroll
        for (int n = 0; n < 4; ++n)
          acc[m][n] = __builtin_amdgcn_mfma_f32_16x16x32_bf16(a[m], bb[n], acc[m][n], 0, 0, 0);
    }
    __syncthreads();
  }

  float* pb = partial + (size_t)blockIdx.x * (128 * 65);
#pragma unroll
  for (int m = 0; m < 2; ++m)
#pragma unroll
    for (int n = 0; n < 4; ++n) {
      int d = n * 16 + (lane & 15);
#pragma unroll
      for (int r = 0; r < 4; ++r) {
        int f = wave * 32 + m * 16 + (lane >> 4) * 4 + r;
        pb[f * 65 + d] = acc[m][n][r];
      }
    }
  ksmem[tid] = ks;
  __syncthreads();
  if (tid < 128) pb[tid * 65 + 64] = ksmem[2 * tid] + ksmem[2 * tid + 1];
}

// reduce partials -> KVT [bh][80 rows][128 f] bf16 (row 64 = Ksum, 65..79 = 0)
__global__ __launch_bounds__(256) void kv_reduce_kernel(
    const float* __restrict__ partial, u16* __restrict__ KVT) {
  const int bh = blockIdx.x, tid = threadIdx.x;
  for (int e = tid; e < 8320; e += 256) {
    float s = 0.f;
#pragma unroll
    for (int c = 0; c < 8; ++c) s += partial[(size_t)(bh * 8 + c) * 8320 + e];
    int f = e / 65, col = e % 65;
    KVT[((size_t)bh * 80 + col) * 128 + f] = f2bf(s);
  }
  for (int i = tid; i < 15 * 128; i += 256)
    KVT[((size_t)bh * 80 + 65) * 128 + i] = 0;
}

// ---------------- QKV = Qp @ KV, Z via 5th N-frag, divide -> A bf16 ----------------
__global__ __launch_bounds__(256) void qkv_div_kernel(
    const u16* __restrict__ Qp, const u16* __restrict__ KVT, u16* __restrict__ A) {
  __shared__ u16 smem2[26624];
  u16* Qs = smem2;          // [128 s][128 f]
  u16* Ks = smem2 + 16384;  // [80 rows][128 f]
  const int tid = threadIdx.x, lane = tid & 63, wave = tid >> 6;
  const int bh = blockIdx.x >> 6, st = blockIdx.x & 63;

  stage_r256<128>((const uint8_t*)(Qp + ((size_t)bh * 8192 + st * 128) * 128), 256,
                  Qs, wave, lane);
  stage_r256<80>((const uint8_t*)(KVT + (size_t)bh * 80 * 128), 256, Ks, wave, lane);
  __syncthreads();

  f32x4 acc[2][5];
#pragma unroll
  for (int m = 0; m < 2; ++m)
#pragma unroll
    for (int n = 0; n < 5; ++n) acc[m][n] = (f32x4){0.f, 0.f, 0.f, 0.f};

#pragma unroll
  for (int kk = 0; kk < 4; ++kk) {
    const int ko = kk * 32 + (lane >> 4) * 8;
    bf16x8 a[2], bb[5];
#pragma unroll
    for (int m = 0; m < 2; ++m)
      a[m] = *(const bf16x8*)&Qs[(size_t)(wave * 32 + m * 16 + (lane & 15)) * 128 + ko];
#pragma unroll
    for (int n = 0; n < 5; ++n)
      bb[n] = *(const bf16x8*)&Ks[(size_t)(n * 16 + (lane & 15)) * 128 + ko];
#pragma unroll
    for (int m = 0; m < 2; ++m)
#pragma unroll
      for (int n = 0; n < 5; ++n)
        acc[m][n] = __builtin_amdgcn_mfma_f32_16x16x32_bf16(a[m], bb[n], acc[m][n], 0, 0, 0);
  }

  const int b_ = bh >> 4, h = bh & 15;
#pragma unroll
  for (int m = 0; m < 2; ++m) {
#pragma unroll
    for (int r = 0; r < 4; ++r) {
      float z = fmaxf(__shfl(acc[m][4][r], lane & 48), 1e-6f);
      int srow = st * 128 + wave * 32 + m * 16 + (lane >> 4) * 4 + r;
      size_t rowb = ((size_t)b_ * 8192 + srow) * 1024 + h * 64;
#pragma unroll
      for (int n = 0; n < 4; ++n)
        A[rowb + n * 16 + (lane & 15)] = f2bf(acc[m][n][r] / z);
    }
  }
}

// ---------------- out = A @ Wo (fp32 out), 256^2 pipelined ----------------
__global__ __launch_bounds__(512, 2) void gemm_out_kernel(
    const u16* __restrict__ A, const u16* __restrict__ WoT, float* __restrict__ out) {
  __shared__ u16 smem[65536];
  const int tid = threadIdx.x, lane = tid & 63, wave = tid >> 6;
  const int wr = wave >> 2, wc = wave & 3;
  const int xcd = blockIdx.x & 7, ii = blockIdx.x >> 3;   // 512 = 8*64
  const int tn = ii & 3, tm = xcd * 16 + (ii >> 2);

  f32x4 acc[8][4];
#pragma unroll
  for (int m = 0; m < 8; ++m)
#pragma unroll
    for (int n = 0; n < 4; ++n) acc[m][n] = (f32x4){0.f, 0.f, 0.f, 0.f};

  const u16* gA = A + (size_t)tm * 256 * 1024;
  const u16* gB = WoT + (size_t)tn * 256 * 1024;
  gemm_main(gA, gB, smem, acc, wave, lane, wr, wc);

  const int rowb = tm * 256 + wr * 128;
  const int colb = tn * 256 + wc * 64;
#pragma unroll
  for (int am = 0; am < 8; ++am)
#pragma unroll
    for (int n = 0; n < 4; ++n) {
      int row = rowb + am * 16 + (lane >> 4) * 4;
      int col = colb + n * 16 + (lane & 15);
#pragma unroll
      for (int r = 0; r < 4; ++r)
        out[(size_t)(row + r) * 1024 + col] = acc[am][n][r];
    }
}

// ---------------- host ----------------

extern "C" void kernel_launch(void* const* d_in, const int* in_sizes, int n_in,
                              void* d_out, int out_size, void* d_ws, size_t ws_size,
                              hipStream_t stream) {
  const float* x  = (const float*)d_in[0];
  const float* Wq = (const float*)d_in[1];
  const float* Wk = (const float*)d_in[2];
  const float* Wv = (const float*)d_in[3];
  const float* Wo = (const float*)d_in[4];
  const float* rf = (const float*)d_in[5];
  float* out = (float*)d_out;

  if (ws_size < (size_t)411058176) return;   // fail cleanly, don't fault

  u16* ws = (u16*)d_ws;
  u16* xb    = ws;
  u16* Qp    = ws + 33554432UL;
  u16* KpT   = ws + 100663296UL;
  u16* VhT   = ws + 167772160UL;
  u16* wqkvT = ws + 201326592UL;
  u16* woT   = ws + 204472320UL;
  u16* rfT   = ws + 205520896UL;
  float* partial = (float*)xb;          // [512][128][65] f32, alias xb (dead)
  u16* KVT   = wqkvT;                   // [64][80][128] bf16, alias wqkvT (dead)
  u16* Abuf  = xb;                      // [32768][1024] bf16, alias xb

  cast_x_kernel<<<4096, 256, 0, stream>>>(x, xb, 8388608L);
  transpose_cast_kernel<<<1024, 256, 0, stream>>>(Wq, wqkvT,            1024, 1024);
  transpose_cast_kernel<<<1024, 256, 0, stream>>>(Wk, wqkvT + 1048576,  1024, 1024);
  transpose_cast_kernel<<<1024, 256, 0, stream>>>(Wv, wqkvT + 2097152,  1024, 1024);
  transpose_cast_kernel<<<1024, 256, 0, stream>>>(Wo, woT,              1024, 1024);
  transpose_cast_kernel<<<8,    256, 0, stream>>>(rf, rfT,              64,   128);

  gemm_qkv_phi_kernel<<<1536, 512, 0, stream>>>(xb, wqkvT, rfT, Qp, KpT, VhT);
  kv_partial_kernel<<<512, 256, 0, stream>>>(KpT, VhT, partial);
  kv_reduce_kernel<<<64, 256, 0, stream>>>(partial, KVT);
  qkv_div_kernel<<<4096, 256, 0, stream>>>(Qp, KVT, Abuf);
  gemm_out_kernel<<<512, 512, 0, stream>>>(Abuf, woT, out);
}